// Round 2
// baseline (215.792 us; speedup 1.0000x reference)
//
#include <hip/hip_runtime.h>

// Embedding gather: out[r, :] = table[ids[r], :]
//   ids:   [819200] int32, values in [0, 1e6)
//   table: [1e6, 32] fp32 -> [1e6 * 8] float4 (row = 128 B = 8 float4)
//   out:   [819200, 32] fp32 -> [6553600] float4
//
// Layout: 8 consecutive lanes cover one 128 B row -> gathered reads and
// writes are both coalesced 128 B segments. ids[row] is a same-address
// broadcast across those 8 lanes.
//
// R2 changes vs R1:
//  - nontemporal stores: out is write-once; don't let 105 MB of output
//    write-allocate into L2/L3 and evict table rows (repeat lookups
//    ~260k/819k want to hit Infinity Cache).
//  - 2 elements per thread (contiguous halves): both gathers in flight
//    before either store -> 2x memory-level parallelism vs HBM latency.

typedef float v4f __attribute__((ext_vector_type(4)));

__global__ void embed_gather_kernel(const int* __restrict__ ids,
                                    const v4f* __restrict__ table,
                                    v4f* __restrict__ out,
                                    int half_vec) {
    int i = blockIdx.x * blockDim.x + threadIdx.x;
    if (i >= half_vec) return;
    int j = i + half_vec;

    int row0 = i >> 3, sub0 = i & 7;
    int row1 = j >> 3, sub1 = j & 7;

    int id0 = ids[row0];
    int id1 = ids[row1];

    // issue both gathers before either store (MLP)
    v4f v0 = table[(long)id0 * 8 + sub0];
    v4f v1 = table[(long)id1 * 8 + sub1];

    __builtin_nontemporal_store(v0, out + i);
    __builtin_nontemporal_store(v1, out + j);
}

extern "C" void kernel_launch(void* const* d_in, const int* in_sizes, int n_in,
                              void* d_out, int out_size, void* d_ws, size_t ws_size,
                              hipStream_t stream) {
    const int* ids    = (const int*)d_in[0];    // [BATCH*HIST]
    const v4f* table  = (const v4f*)d_in[1];    // [VOCAB*8]
    v4f* out          = (v4f*)d_out;            // [BATCH*HIST*8]

    int n_rows   = in_sizes[0];       // 819200
    int n_vec    = n_rows * 8;        // 6,553,600 float4s
    int half_vec = n_vec / 2;         // each thread does i and i+half

    const int block = 256;
    int grid = (half_vec + block - 1) / block;
    embed_gather_kernel<<<grid, block, 0, stream>>>(ids, table, out, half_vec);
}

// Round 3
// 214.053 us; speedup vs baseline: 1.0081x; 1.0081x over previous
//
#include <hip/hip_runtime.h>

// Embedding gather: out[r, :] = table[ids[r], :]
//   ids:   [819200] int32, values in [0, 1e6)
//   table: [1e6, 32] fp32 -> [1e6 * 8] float4 (row = 128 B = 8 float4)
//   out:   [819200, 32] fp32 -> [6553600] float4
//
// Layout: 8 consecutive lanes cover one 128 B row -> gathered reads and
// writes are both coalesced 128 B segments; ids[row] is an 8-lane
// same-address broadcast.
//
// R3: 4 gathers in flight per thread (quarter-strided so each quarter
// stays contiguous/coalesced). All 4 id loads, then all 4 table loads,
// then all 4 stores -> 4x memory-level parallelism vs R1. This is the
// discriminating experiment: latency-bound -> ~-10 us; BW-bound -> neutral.

typedef float v4f __attribute__((ext_vector_type(4)));

__global__ void embed_gather_kernel(const int* __restrict__ ids,
                                    const v4f* __restrict__ table,
                                    v4f* __restrict__ out,
                                    int quarter_vec) {
    int i0 = blockIdx.x * blockDim.x + threadIdx.x;
    if (i0 >= quarter_vec) return;
    int i1 = i0 + quarter_vec;
    int i2 = i1 + quarter_vec;
    int i3 = i2 + quarter_vec;

    int id0 = ids[i0 >> 3];
    int id1 = ids[i1 >> 3];
    int id2 = ids[i2 >> 3];
    int id3 = ids[i3 >> 3];

    v4f v0 = table[(long)id0 * 8 + (i0 & 7)];
    v4f v1 = table[(long)id1 * 8 + (i1 & 7)];
    v4f v2 = table[(long)id2 * 8 + (i2 & 7)];
    v4f v3 = table[(long)id3 * 8 + (i3 & 7)];

    __builtin_nontemporal_store(v0, out + i0);
    __builtin_nontemporal_store(v1, out + i1);
    __builtin_nontemporal_store(v2, out + i2);
    __builtin_nontemporal_store(v3, out + i3);
}

extern "C" void kernel_launch(void* const* d_in, const int* in_sizes, int n_in,
                              void* d_out, int out_size, void* d_ws, size_t ws_size,
                              hipStream_t stream) {
    const int* ids    = (const int*)d_in[0];    // [BATCH*HIST]
    const v4f* table  = (const v4f*)d_in[1];    // [VOCAB*8]
    v4f* out          = (v4f*)d_out;            // [BATCH*HIST*8]

    int n_rows      = in_sizes[0];    // 819200
    int n_vec       = n_rows * 8;     // 6,553,600 float4s
    int quarter_vec = n_vec / 4;      // each thread does 4, quarter-strided

    const int block = 256;
    int grid = (quarter_vec + block - 1) / block;
    embed_gather_kernel<<<grid, block, 0, stream>>>(ids, table, out, quarter_vec);
}